// Round 3
// baseline (170.181 us; speedup 1.0000x reference)
//
#include <hip/hip_runtime.h>

typedef unsigned short u16;
typedef short bf16x8 __attribute__((ext_vector_type(8)));
typedef float f32x4 __attribute__((ext_vector_type(4)));
typedef u16 u16x4 __attribute__((ext_vector_type(4)));

__device__ __forceinline__ float b2f(u16 h) {
  unsigned u = ((unsigned)h) << 16;
  return __builtin_bit_cast(float, u);
}
__device__ __forceinline__ u16 f2b(float f) {
  unsigned u = __builtin_bit_cast(unsigned, f);
  u = u + 0x7fffu + ((u >> 16) & 1u);   // round-to-nearest-even
  return (u16)(u >> 16);
}
__device__ __forceinline__ void gld_lds16(const void* g, void* l) {
  __builtin_amdgcn_global_load_lds(
      (__attribute__((address_space(1))) void*)(g),
      (__attribute__((address_space(3))) void*)(l), 16, 0, 0);
}

// ---------------------------------------------------------------------------
// prep (merged): blocks [0,160): fp32 [o][c] weights -> bf16 STAGED layout
//   [layer][s8(32)][m(256)][8]  (a wave's A-frag reads are 256B-contiguous)
//   layers: 0,1 = post_w[0..1]; 2,3,4 = pre_w[0..2]
// blocks [160,416): x [2][256][1024] fp32 -> xt [2048][256] bf16 (transpose)
// ---------------------------------------------------------------------------
__global__ void dense_edge_prep(const float* __restrict__ x,
                                const float* __restrict__ pre_w,
                                const float* __restrict__ post_w,
                                u16* __restrict__ wb, u16* __restrict__ xt) {
  const int blk = blockIdx.x;
  const int t = threadIdx.x;
  if (blk < 160) {
    const int id = blk * 256 + t;      // 40960 slots of 8 elems
    const int layer = id >> 13;        // 0..4
    const int sid = id & 8191;
    const int m = sid >> 5;
    const int s8 = sid & 31;
    const float* src = (layer < 2) ? (post_w + layer * 65536)
                                   : (pre_w + (layer - 2) * 65536);
    u16* dst = wb + layer * 65536;
    f32x4 a = *(const f32x4*)(src + m * 256 + s8 * 8);
    f32x4 c = *(const f32x4*)(src + m * 256 + s8 * 8 + 4);
    bf16x8 o;
#pragma unroll
    for (int j = 0; j < 4; j++) o[j] = (short)f2b(a[j]);
#pragma unroll
    for (int j = 0; j < 4; j++) o[4 + j] = (short)f2b(c[j]);
    *(bf16x8*)(dst + (s8 * 256 + m) * 8) = o;
  } else {
    __shared__ float tile[32 * 65];
    const int xb = blk - 160;          // 2 b x 8 ctile x 16 hwtile = 256
    const int b = xb >> 7;
    const int ct = (xb >> 4) & 7;
    const int ht = xb & 15;
    const int c0 = ct * 32, hw0 = ht * 64;
#pragma unroll
    for (int rep = 0; rep < 8; rep++) {
      const int idx = rep * 256 + t;
      const int cl = idx >> 6, hl = idx & 63;
      tile[cl * 65 + hl] = x[(b * 256 + c0 + cl) * 1024 + hw0 + hl];
    }
    __syncthreads();
    const int hl = t >> 2, c8 = t & 3;
    bf16x8 o;
#pragma unroll
    for (int i = 0; i < 8; i++) o[i] = (short)f2b(tile[(c8 * 8 + i) * 65 + hl]);
    *(bf16x8*)(xt + (b * 1024 + hw0 + hl) * 256 + c0 + c8 * 8) = o;
  }
}

// ---------------------------------------------------------------------------
// pre_gemm: 3-layer 1x1-conv chain on 2048 nodes, bf16 MFMA (R1 version,
// staged-layout weight reads). Output flat[node][c] bf16.
// ---------------------------------------------------------------------------
__global__ __launch_bounds__(256, 2) void dense_edge_pre(
    const u16* __restrict__ xt, const u16* __restrict__ wpre,
    const float* __restrict__ preb, u16* __restrict__ flat) {
  __shared__ u16 feat[2][4096];  // [32 s8][16 n][8] each
  const int t = threadIdx.x;
  const int wv = t >> 6, ln = t & 63;
  const int nb = blockIdx.x * 16;
  const int q4 = ln >> 4, r15 = ln & 15;

#pragma unroll
  for (int i = 0; i < 2; i++) {
    const int slot = wv * 128 + i * 64 + ln;
    const int s8 = slot >> 4, nl = slot & 15;
    gld_lds16(xt + (nb + nl) * 256 + s8 * 8, &feat[0][slot * 8]);
  }
  __syncthreads();

#pragma unroll
  for (int l = 0; l < 3; l++) {
    const u16* wl = wpre + l * 65536;
    f32x4 acc[4];
    f32x4 zero = {0.f, 0.f, 0.f, 0.f};
#pragma unroll
    for (int mt = 0; mt < 4; mt++) acc[mt] = zero;
#pragma unroll
    for (int s = 0; s < 8; s++) {
      bf16x8 bv = *(const bf16x8*)(&feat[l & 1][((s * 4 + q4) * 16 + r15) * 8]);
#pragma unroll
      for (int mt = 0; mt < 4; mt++) {
        bf16x8 av = *(const bf16x8*)(wl + ((s * 4 + q4) * 256 + wv * 64 + mt * 16 + r15) * 8);
        acc[mt] = __builtin_amdgcn_mfma_f32_16x16x32_bf16(av, bv, acc[mt], 0, 0, 0);
      }
    }
    if (l < 2) {
#pragma unroll
      for (int mt = 0; mt < 4; mt++) {
        const int o = wv * 64 + mt * 16 + q4 * 4;
        f32x4 bb = *(const f32x4*)(preb + l * 256 + o);
        u16x4 pk;
#pragma unroll
        for (int r = 0; r < 4; r++) {
          float v = fmaxf(acc[mt][r] + bb[r], 0.f);
          pk[r] = f2b(v);
        }
        *(u16x4*)(&feat[(l + 1) & 1][((o >> 3) * 16 + r15) * 8 + (o & 7)]) = pk;
      }
      __syncthreads();
    } else {
#pragma unroll
      for (int mt = 0; mt < 4; mt++) {
        const int o = wv * 64 + mt * 16 + q4 * 4;
        f32x4 bb = *(const f32x4*)(preb + 512 + o);
        u16x4 pk;
#pragma unroll
        for (int r = 0; r < 4; r++) pk[r] = f2b(acc[mt][r] + bb[r]);  // no relu
        *(u16x4*)(flat + (nb + r15) * 256 + o) = pk;
      }
    }
  }
}

// ---------------------------------------------------------------------------
// g1: W1-stationary-in-registers. Block = (b, pt, qgroup of 4 q-tiles).
// Per tile: gather XX -> LDS, 8-stage MFMA from reg-A / LDS-B,
// relu+b1 -> T1 tile (staged layout [tile][s8(32)][n(64)][8]) in global ws.
// LDS 32 KB -> 2 blocks/CU; af_w = 128 VGPR, acc = 64 VGPR.
// ---------------------------------------------------------------------------
__global__ __launch_bounds__(256, 2) void dense_edge_g1(
    const u16* __restrict__ flat, const int* __restrict__ pidx,
    const int* __restrict__ cidx, const u16* __restrict__ w1s,
    const float* __restrict__ b1, u16* __restrict__ t1) {
  __shared__ u16 xxbuf[16384];     // 32 KB: [s8(32)][n(64)][8]
  const int t = threadIdx.x;
  const int wv = t >> 6, ln = t & 63;
  const int q4 = ln >> 4, r15 = ln & 15;
  const int blk = blockIdx.x;      // 512: b(2) x pt(32) x qg(8)
  const int b = blk >> 8;
  const int pt = (blk >> 3) & 31;
  const int qg = blk & 7;
  const int p0 = pt * 8;

  // load this wave's W1 fragments into registers (coalesced 256B segments)
  bf16x8 af_w[4][8];
#pragma unroll
  for (int s = 0; s < 8; s++)
#pragma unroll
    for (int mt = 0; mt < 4; mt++)
      af_w[mt][s] = *(const bf16x8*)(w1s + ((s * 4 + q4) * 256 + wv * 64 + mt * 16 + r15) * 8);

#pragma unroll 1
  for (int j = 0; j < 4; j++) {
    const int qt = qg * 4 + j;
    const int q0 = qt * 8;
    // gather/build XX: thread = (n = ln, c-block = wv)
    {
      const int n = ln;
      const int pn = pidx[b * 256 + p0 + (n >> 3)];
      const int qn = cidx[b * 256 + q0 + (n & 7)];
      const u16* prow = flat + pn * 256 + wv * 64;
      const u16* qrow = flat + qn * 256 + wv * 64;
#pragma unroll
      for (int i = 0; i < 8; i++) {
        bf16x8 av = *(const bf16x8*)(prow + i * 8);
        bf16x8 bv = *(const bf16x8*)(qrow + i * 8);
        bf16x8 ov;
#pragma unroll
        for (int jj = 0; jj < 8; jj++) {
          float d = b2f((u16)av[jj]) - b2f((u16)bv[jj]);
          ov[jj] = (short)f2b(d * d);
        }
        *(bf16x8*)(xxbuf + ((wv * 8 + i) * 64 + n) * 8) = ov;
      }
    }
    __syncthreads();   // XX visible

    f32x4 acc[4][4];
    {
      f32x4 zero = {0.f, 0.f, 0.f, 0.f};
#pragma unroll
      for (int mt = 0; mt < 4; mt++)
#pragma unroll
        for (int nt = 0; nt < 4; nt++) acc[mt][nt] = zero;
    }
#pragma unroll
    for (int s = 0; s < 8; s++) {
      bf16x8 bfr[4];
#pragma unroll
      for (int nt = 0; nt < 4; nt++)
        bfr[nt] = *(const bf16x8*)(xxbuf + ((s * 4 + q4) * 64 + nt * 16 + r15) * 8);
#pragma unroll
      for (int mt = 0; mt < 4; mt++)
#pragma unroll
        for (int nt = 0; nt < 4; nt++)
          acc[mt][nt] = __builtin_amdgcn_mfma_f32_16x16x32_bf16(af_w[mt][s], bfr[nt], acc[mt][nt], 0, 0, 0);
    }
    __syncthreads();   // all xxbuf reads done before next j overwrites

    // T1 writeback: relu + b1, staged tile layout
    u16* tdst = t1 + (((b * 32 + pt) * 32 + qt) << 14);
#pragma unroll
    for (int mt = 0; mt < 4; mt++) {
      const int o = wv * 64 + mt * 16 + q4 * 4;
      f32x4 bb = *(const f32x4*)(b1 + o);
#pragma unroll
      for (int nt = 0; nt < 4; nt++) {
        const int nn = nt * 16 + r15;
        u16x4 pk;
#pragma unroll
        for (int r = 0; r < 4; r++) {
          float v = fmaxf(acc[mt][nt][r] + bb[r], 0.f);
          pk[r] = f2b(v);
        }
        *(u16x4*)(tdst + ((o >> 3) * 64 + nn) * 8 + (o & 7)) = pk;
      }
    }
  }
}

// ---------------------------------------------------------------------------
// g2: W2-stationary-in-registers. Per tile: T1 tile -> LDS (global_load_lds,
// pure copy), GEMM2, register-level W3 epilogue (relu+b2 folded), out write.
// ---------------------------------------------------------------------------
__global__ __launch_bounds__(256, 2) void dense_edge_g2(
    const u16* __restrict__ t1, const u16* __restrict__ w2s,
    const float* __restrict__ b2, const float* __restrict__ w3,
    const float* __restrict__ b3, float* __restrict__ out) {
  __shared__ u16 xxbuf[16384];       // 32 KB
  __shared__ float pbuf[4][2][64];   // 2 KB cross-wave partials
  const int t = threadIdx.x;
  const int wv = t >> 6, ln = t & 63;
  const int q4 = ln >> 4, r15 = ln & 15;
  const int blk = blockIdx.x;        // 512 blocks x 4 tiles

  bf16x8 af_w[4][8];
#pragma unroll
  for (int s = 0; s < 8; s++)
#pragma unroll
    for (int mt = 0; mt < 4; mt++)
      af_w[mt][s] = *(const bf16x8*)(w2s + ((s * 4 + q4) * 256 + wv * 64 + mt * 16 + r15) * 8);

#pragma unroll 1
  for (int j = 0; j < 4; j++) {
    const int tile = blk * 4 + j;
    const int b = tile >> 10;
    const int pt = (tile >> 5) & 31;
    const int qt = tile & 31;
    const u16* tsrc = t1 + ((long)tile << 14);
#pragma unroll
    for (int i = 0; i < 8; i++)
      gld_lds16(tsrc + (i * 256 + t) * 8, xxbuf + (i * 256 + t) * 8);
    __syncthreads();   // copy drained

    f32x4 acc[4][4];
    {
      f32x4 zero = {0.f, 0.f, 0.f, 0.f};
#pragma unroll
      for (int mt = 0; mt < 4; mt++)
#pragma unroll
        for (int nt = 0; nt < 4; nt++) acc[mt][nt] = zero;
    }
#pragma unroll
    for (int s = 0; s < 8; s++) {
      bf16x8 bfr[4];
#pragma unroll
      for (int nt = 0; nt < 4; nt++)
        bfr[nt] = *(const bf16x8*)(xxbuf + ((s * 4 + q4) * 64 + nt * 16 + r15) * 8);
#pragma unroll
      for (int mt = 0; mt < 4; mt++)
#pragma unroll
        for (int nt = 0; nt < 4; nt++)
          acc[mt][nt] = __builtin_amdgcn_mfma_f32_16x16x32_bf16(af_w[mt][s], bfr[nt], acc[mt][nt], 0, 0, 0);
    }

    // register epilogue: part[o3][nt] = sum over this lane's 16 rows of
    // w3[o3][row] * relu(acc + b2[row])
    float part[2][4] = {{0.f, 0.f, 0.f, 0.f}, {0.f, 0.f, 0.f, 0.f}};
#pragma unroll
    for (int mt = 0; mt < 4; mt++) {
      const int o = wv * 64 + mt * 16 + q4 * 4;
      f32x4 bb = *(const f32x4*)(b2 + o);
      f32x4 w3a = *(const f32x4*)(w3 + o);
      f32x4 w3b = *(const f32x4*)(w3 + 256 + o);
#pragma unroll
      for (int nt = 0; nt < 4; nt++) {
#pragma unroll
        for (int r = 0; r < 4; r++) {
          float v = fmaxf(acc[mt][nt][r] + bb[r], 0.f);
          part[0][nt] += v * w3a[r];
          part[1][nt] += v * w3b[r];
        }
      }
    }
    // reduce across q4 (lanes ^16, ^32)
#pragma unroll
    for (int o3 = 0; o3 < 2; o3++)
#pragma unroll
      for (int nt = 0; nt < 4; nt++) {
        part[o3][nt] += __shfl_xor(part[o3][nt], 16, 64);
        part[o3][nt] += __shfl_xor(part[o3][nt], 32, 64);
      }
    if (q4 == 0) {
#pragma unroll
      for (int o3 = 0; o3 < 2; o3++)
#pragma unroll
        for (int nt = 0; nt < 4; nt++)
          pbuf[wv][o3][nt * 16 + r15] = part[o3][nt];
    }
    __syncthreads();   // partials visible
    if (t < 128) {
      const int o3 = t >> 6;
      const int n = t & 63;
      float v = pbuf[0][o3][n] + pbuf[1][o3][n] + pbuf[2][o3][n] + pbuf[3][o3][n] + b3[o3];
      out[((b * 2 + o3) * 256 + pt * 8 + (n >> 3)) * 256 + qt * 8 + (n & 7)] = v;
    }
    __syncthreads();   // pbuf/xxbuf free for next tile
  }
}

// ---------------------------------------------------------------------------
extern "C" void kernel_launch(void* const* d_in, const int* in_sizes, int n_in,
                              void* d_out, int out_size, void* d_ws, size_t ws_size,
                              hipStream_t stream) {
  (void)in_sizes; (void)n_in; (void)out_size; (void)ws_size;
  const float* x          = (const float*)d_in[0];
  const int*   pidx       = (const int*)d_in[1];
  const int*   cidx       = (const int*)d_in[2];
  const float* pre_w      = (const float*)d_in[3];
  const float* pre_b      = (const float*)d_in[4];
  const float* post_w     = (const float*)d_in[5];
  const float* post_b     = (const float*)d_in[6];
  const float* post_out_w = (const float*)d_in[7];
  const float* post_out_b = (const float*)d_in[8];
  float* out = (float*)d_out;

  u16* ws   = (u16*)d_ws;
  u16* wb   = ws;              // staged bf16 weights: w1,w2,pre0,pre1,pre2
  u16* w1s  = wb;
  u16* w2s  = wb + 65536;
  u16* wpre = wb + 131072;
  u16* xt   = ws + 327680;     // x_t bf16 [2048][256]
  u16* flat = ws + 851968;     // node features bf16 [2048][256]
  u16* t1   = ws + 1376256;    // T1 tiles: 2048 x 16384 u16 = 64 MB

  dense_edge_prep<<<416, 256, 0, stream>>>(x, pre_w, post_w, wb, xt);
  dense_edge_pre<<<128, 256, 0, stream>>>(xt, wpre, pre_b, flat);
  dense_edge_g1<<<512, 256, 0, stream>>>(flat, pidx, cidx, w1s, post_b, t1);
  dense_edge_g2<<<512, 256, 0, stream>>>(t1, w2s, post_b + 256,
                                         post_out_w, post_out_b, out);
}

// Round 4
// 124.258 us; speedup vs baseline: 1.3696x; 1.3696x over previous
//
#include <hip/hip_runtime.h>

typedef unsigned short u16;
typedef short bf16x8 __attribute__((ext_vector_type(8)));
typedef float f32x4 __attribute__((ext_vector_type(4)));
typedef u16 u16x4 __attribute__((ext_vector_type(4)));

__device__ __forceinline__ float b2f(u16 h) {
  unsigned u = ((unsigned)h) << 16;
  return __builtin_bit_cast(float, u);
}
__device__ __forceinline__ u16 f2b(float f) {
  unsigned u = __builtin_bit_cast(unsigned, f);
  u = u + 0x7fffu + ((u >> 16) & 1u);   // round-to-nearest-even
  return (u16)(u >> 16);
}
__device__ __forceinline__ void gld_lds16(const void* g, void* l) {
  __builtin_amdgcn_global_load_lds(
      (__attribute__((address_space(1))) void*)(g),
      (__attribute__((address_space(3))) void*)(l), 16, 0, 0);
}

// ---------------------------------------------------------------------------
// prep (merged): blocks [0,160): fp32 [o][c] weights -> bf16 STAGED layout
//   [layer][s8(32)][m(256)][8]  (a wave's A-frag reads are 256B-contiguous)
//   layers: 0,1 = post_w[0..1]; 2,3,4 = pre_w[0..2]
// blocks [160,416): x [2][256][1024] fp32 -> xt [2048][256] bf16 (transpose)
// ---------------------------------------------------------------------------
__global__ void dense_edge_prep(const float* __restrict__ x,
                                const float* __restrict__ pre_w,
                                const float* __restrict__ post_w,
                                u16* __restrict__ wb, u16* __restrict__ xt) {
  const int blk = blockIdx.x;
  const int t = threadIdx.x;
  if (blk < 160) {
    const int id = blk * 256 + t;      // 40960 slots of 8 elems
    const int layer = id >> 13;        // 0..4
    const int sid = id & 8191;
    const int m = sid >> 5;
    const int s8 = sid & 31;
    const float* src = (layer < 2) ? (post_w + layer * 65536)
                                   : (pre_w + (layer - 2) * 65536);
    u16* dst = wb + layer * 65536;
    f32x4 a = *(const f32x4*)(src + m * 256 + s8 * 8);
    f32x4 c = *(const f32x4*)(src + m * 256 + s8 * 8 + 4);
    bf16x8 o;
#pragma unroll
    for (int j = 0; j < 4; j++) o[j] = (short)f2b(a[j]);
#pragma unroll
    for (int j = 0; j < 4; j++) o[4 + j] = (short)f2b(c[j]);
    *(bf16x8*)(dst + (s8 * 256 + m) * 8) = o;
  } else {
    __shared__ float tile[32 * 65];
    const int xb = blk - 160;          // 2 b x 8 ctile x 16 hwtile = 256
    const int b = xb >> 7;
    const int ct = (xb >> 4) & 7;
    const int ht = xb & 15;
    const int c0 = ct * 32, hw0 = ht * 64;
#pragma unroll
    for (int rep = 0; rep < 8; rep++) {
      const int idx = rep * 256 + t;
      const int cl = idx >> 6, hl = idx & 63;
      tile[cl * 65 + hl] = x[(b * 256 + c0 + cl) * 1024 + hw0 + hl];
    }
    __syncthreads();
    const int hl = t >> 2, c8 = t & 3;
    bf16x8 o;
#pragma unroll
    for (int i = 0; i < 8; i++) o[i] = (short)f2b(tile[(c8 * 8 + i) * 65 + hl]);
    *(bf16x8*)(xt + (b * 1024 + hw0 + hl) * 256 + c0 + c8 * 8) = o;
  }
}

// ---------------------------------------------------------------------------
// pre_gemm: 3-layer 1x1-conv chain on 2048 nodes, bf16 MFMA.
// Block = 16 nodes. A = W staged layout (global/L2), B = features in LDS
// ping-pong. Output flat[node][c] bf16.
// ---------------------------------------------------------------------------
__global__ __launch_bounds__(256, 2) void dense_edge_pre(
    const u16* __restrict__ xt, const u16* __restrict__ wpre,
    const float* __restrict__ preb, u16* __restrict__ flat) {
  __shared__ u16 feat[2][4096];  // [32 s8][16 n][8] each
  const int t = threadIdx.x;
  const int wv = t >> 6, ln = t & 63;
  const int nb = blockIdx.x * 16;
  const int q4 = ln >> 4, r15 = ln & 15;

#pragma unroll
  for (int i = 0; i < 2; i++) {
    const int slot = wv * 128 + i * 64 + ln;
    const int s8 = slot >> 4, nl = slot & 15;
    gld_lds16(xt + (nb + nl) * 256 + s8 * 8, &feat[0][slot * 8]);
  }
  __syncthreads();

#pragma unroll
  for (int l = 0; l < 3; l++) {
    const u16* wl = wpre + l * 65536;
    f32x4 acc[4];
    f32x4 zero = {0.f, 0.f, 0.f, 0.f};
#pragma unroll
    for (int mt = 0; mt < 4; mt++) acc[mt] = zero;
#pragma unroll
    for (int s = 0; s < 8; s++) {
      bf16x8 bv = *(const bf16x8*)(&feat[l & 1][((s * 4 + q4) * 16 + r15) * 8]);
#pragma unroll
      for (int mt = 0; mt < 4; mt++) {
        bf16x8 av = *(const bf16x8*)(wl + ((s * 4 + q4) * 256 + wv * 64 + mt * 16 + r15) * 8);
        acc[mt] = __builtin_amdgcn_mfma_f32_16x16x32_bf16(av, bv, acc[mt], 0, 0, 0);
      }
    }
    if (l < 2) {
#pragma unroll
      for (int mt = 0; mt < 4; mt++) {
        const int o = wv * 64 + mt * 16 + q4 * 4;
        f32x4 bb = *(const f32x4*)(preb + l * 256 + o);
        u16x4 pk;
#pragma unroll
        for (int r = 0; r < 4; r++) {
          float v = fmaxf(acc[mt][r] + bb[r], 0.f);
          pk[r] = f2b(v);
        }
        *(u16x4*)(&feat[(l + 1) & 1][((o >> 3) * 16 + r15) * 8 + (o & 7)]) = pk;
      }
      __syncthreads();
    } else {
#pragma unroll
      for (int mt = 0; mt < 4; mt++) {
        const int o = wv * 64 + mt * 16 + q4 * 4;
        f32x4 bb = *(const f32x4*)(preb + 512 + o);
        u16x4 pk;
#pragma unroll
        for (int r = 0; r < 4; r++) pk[r] = f2b(acc[mt][r] + bb[r]);  // no relu
        *(u16x4*)(flat + (nb + r15) * 256 + o) = pk;
      }
    }
  }
}

// ---------------------------------------------------------------------------
// main: fused GEMM1+GEMM2+W3 with wave specialization.
// Block = 512 threads (8 waves). Waves 0-3: W1 in regs -> build XX, GEMM1.
// Waves 4-7: W2 in regs -> GEMM2 + W3 epilogue. T1 lives only in LDS.
// 256 blocks x 8 tiles (same pt per block -> p-gather constant).
// Per tile step: P1 = XX-build(j) || GEMM2(j-1)+partials; barrier;
//                P2 = GEMM1(j)->t1buf || pbuf-sum+out(j-1); barrier.
// ---------------------------------------------------------------------------
__global__ __launch_bounds__(512, 2) void dense_edge_main(
    const u16* __restrict__ flat, const int* __restrict__ pidx,
    const int* __restrict__ cidx, const u16* __restrict__ w1s,
    const u16* __restrict__ w2s, const float* __restrict__ b1,
    const float* __restrict__ b2, const float* __restrict__ w3,
    const float* __restrict__ b3, float* __restrict__ out) {
  __shared__ u16 xxbuf[16384];      // 32 KB [s8(32)][n(64)][8]
  __shared__ u16 t1buf[16384];      // 32 KB, same layout
  __shared__ float pbuf[4][2][64];  // 2 KB consumer partials

  const int t = threadIdx.x;
  const int wv = t >> 6;
  const int ln = t & 63;
  const int q4 = ln >> 4, r15 = ln & 15;
  const bool prod = wv < 4;
  const int cw = wv & 3;            // lane-group / m-quarter within role
  const int blk = blockIdx.x;
  const int tile0 = blk * 8;
  const int b = tile0 >> 10;
  const int pt = (tile0 >> 5) & 31;
  const int qt0 = tile0 & 31;
  const int p0 = pt * 8;

  // role weights into registers (coalesced 256B segments from staged layout)
  const u16* wsrc = prod ? w1s : w2s;
  bf16x8 af_w[4][8];
#pragma unroll
  for (int s = 0; s < 8; s++)
#pragma unroll
    for (int mt = 0; mt < 4; mt++)
      af_w[mt][s] = *(const bf16x8*)(wsrc + ((s * 4 + q4) * 256 + cw * 64 + mt * 16 + r15) * 8);

  // producer: p-row pointer (constant across the block's 8 tiles)
  int pn = 0;
  if (prod) pn = pidx[b * 256 + p0 + (ln >> 3)];
  const u16* prow = flat + pn * 256 + cw * 64;

#pragma unroll 1
  for (int j = 0; j <= 8; j++) {
    // ---------------- P1 ----------------
    if (prod) {
      if (j < 8) {
        const int qn = cidx[b * 256 + (qt0 + j) * 8 + (ln & 7)];
        const u16* qrow = flat + qn * 256 + cw * 64;
#pragma unroll
        for (int i = 0; i < 8; i++) {
          bf16x8 av = *(const bf16x8*)(prow + i * 8);
          bf16x8 bv = *(const bf16x8*)(qrow + i * 8);
          bf16x8 ov;
#pragma unroll
          for (int jj = 0; jj < 8; jj++) {
            float d = b2f((u16)av[jj]) - b2f((u16)bv[jj]);
            ov[jj] = (short)f2b(d * d);
          }
          *(bf16x8*)(xxbuf + ((cw * 8 + i) * 64 + ln) * 8) = ov;
        }
      }
    } else if (j > 0) {
      // GEMM2 on tile j-1 from t1buf
      f32x4 acc[4][4];
      {
        f32x4 zero = {0.f, 0.f, 0.f, 0.f};
#pragma unroll
        for (int mt = 0; mt < 4; mt++)
#pragma unroll
          for (int nt = 0; nt < 4; nt++) acc[mt][nt] = zero;
      }
#pragma unroll
      for (int s = 0; s < 8; s++) {
        bf16x8 bfr[4];
#pragma unroll
        for (int nt = 0; nt < 4; nt++)
          bfr[nt] = *(const bf16x8*)(t1buf + ((s * 4 + q4) * 64 + nt * 16 + r15) * 8);
#pragma unroll
        for (int mt = 0; mt < 4; mt++)
#pragma unroll
          for (int nt = 0; nt < 4; nt++)
            acc[mt][nt] = __builtin_amdgcn_mfma_f32_16x16x32_bf16(af_w[mt][s], bfr[nt], acc[mt][nt], 0, 0, 0);
      }
      // W3 epilogue partials: relu(acc+b2) dotted with w3 rows
      float part[2][4] = {{0.f, 0.f, 0.f, 0.f}, {0.f, 0.f, 0.f, 0.f}};
#pragma unroll
      for (int mt = 0; mt < 4; mt++) {
        const int o = cw * 64 + mt * 16 + q4 * 4;
        f32x4 bb = *(const f32x4*)(b2 + o);
        f32x4 w3a = *(const f32x4*)(w3 + o);
        f32x4 w3b = *(const f32x4*)(w3 + 256 + o);
#pragma unroll
        for (int nt = 0; nt < 4; nt++) {
#pragma unroll
          for (int r = 0; r < 4; r++) {
            float v = fmaxf(acc[mt][nt][r] + bb[r], 0.f);
            part[0][nt] += v * w3a[r];
            part[1][nt] += v * w3b[r];
          }
        }
      }
#pragma unroll
      for (int o3 = 0; o3 < 2; o3++)
#pragma unroll
        for (int nt = 0; nt < 4; nt++) {
          part[o3][nt] += __shfl_xor(part[o3][nt], 16, 64);
          part[o3][nt] += __shfl_xor(part[o3][nt], 32, 64);
        }
      if (q4 == 0) {
#pragma unroll
        for (int o3 = 0; o3 < 2; o3++)
#pragma unroll
          for (int nt = 0; nt < 4; nt++)
            pbuf[cw][o3][nt * 16 + r15] = part[o3][nt];
      }
    }
    __syncthreads();

    // ---------------- P2 ----------------
    if (prod) {
      if (j < 8) {
        f32x4 acc[4][4];
        {
          f32x4 zero = {0.f, 0.f, 0.f, 0.f};
#pragma unroll
          for (int mt = 0; mt < 4; mt++)
#pragma unroll
            for (int nt = 0; nt < 4; nt++) acc[mt][nt] = zero;
        }
#pragma unroll
        for (int s = 0; s < 8; s++) {
          bf16x8 bfr[4];
#pragma unroll
          for (int nt = 0; nt < 4; nt++)
            bfr[nt] = *(const bf16x8*)(xxbuf + ((s * 4 + q4) * 64 + nt * 16 + r15) * 8);
#pragma unroll
          for (int mt = 0; mt < 4; mt++)
#pragma unroll
            for (int nt = 0; nt < 4; nt++)
              acc[mt][nt] = __builtin_amdgcn_mfma_f32_16x16x32_bf16(af_w[mt][s], bfr[nt], acc[mt][nt], 0, 0, 0);
        }
        // relu + b1 -> t1buf (staged layout)
#pragma unroll
        for (int mt = 0; mt < 4; mt++) {
          const int o = cw * 64 + mt * 16 + q4 * 4;
          f32x4 bb = *(const f32x4*)(b1 + o);
#pragma unroll
          for (int nt = 0; nt < 4; nt++) {
            const int nn = nt * 16 + r15;
            u16x4 pk;
#pragma unroll
            for (int r = 0; r < 4; r++) {
              float v = fmaxf(acc[mt][nt][r] + bb[r], 0.f);
              pk[r] = f2b(v);
            }
            *(u16x4*)(t1buf + ((o >> 3) * 64 + nn) * 8 + (o & 7)) = pk;
          }
        }
      }
    } else if (j > 0) {
      const int idx = t & 255;
      if (idx < 128) {
        const int o3 = idx >> 6;
        const int n = idx & 63;
        float v = pbuf[0][o3][n] + pbuf[1][o3][n] + pbuf[2][o3][n] + pbuf[3][o3][n] + b3[o3];
        out[((b * 2 + o3) * 256 + p0 + (n >> 3)) * 256 + (qt0 + j - 1) * 8 + (n & 7)] = v;
      }
    }
    __syncthreads();
  }
}

// ---------------------------------------------------------------------------
extern "C" void kernel_launch(void* const* d_in, const int* in_sizes, int n_in,
                              void* d_out, int out_size, void* d_ws, size_t ws_size,
                              hipStream_t stream) {
  (void)in_sizes; (void)n_in; (void)out_size; (void)ws_size;
  const float* x          = (const float*)d_in[0];
  const int*   pidx       = (const int*)d_in[1];
  const int*   cidx       = (const int*)d_in[2];
  const float* pre_w      = (const float*)d_in[3];
  const float* pre_b      = (const float*)d_in[4];
  const float* post_w     = (const float*)d_in[5];
  const float* post_b     = (const float*)d_in[6];
  const float* post_out_w = (const float*)d_in[7];
  const float* post_out_b = (const float*)d_in[8];
  float* out = (float*)d_out;

  u16* ws   = (u16*)d_ws;
  u16* wb   = ws;              // staged bf16 weights: w1,w2,pre0,pre1,pre2
  u16* w1s  = wb;
  u16* w2s  = wb + 65536;
  u16* wpre = wb + 131072;
  u16* xt   = ws + 327680;     // x_t bf16 [2048][256]
  u16* flat = ws + 851968;     // node features bf16 [2048][256]

  dense_edge_prep<<<416, 256, 0, stream>>>(x, pre_w, post_w, wb, xt);
  dense_edge_pre<<<128, 256, 0, stream>>>(xt, wpre, pre_b, flat);
  dense_edge_main<<<256, 512, 0, stream>>>(flat, pidx, cidx, w1s, w2s,
                                           post_b, post_b + 256,
                                           post_out_w, post_out_b, out);
}